// Round 5
// baseline (82.211 us; speedup 1.0000x reference)
//
#include <hip/hip_runtime.h>
#include <math.h>

#define BB 4
#define CC 256
#define HW (128*128)
#define NLINES 1024          // HW / 16 pixels-per-64B-line
#define NC 19
#define NV 50
#define PP (NC*NV)           // 950
#define INV_T (1.0f/0.07f)
#define PLANE ((size_t)BB * PP * CC)   // elems per bf16 plane
#define RT 60                // row tiles of 16 (60*16=960 >= 950)
#define SRSTRIDE (960*16)    // per-b slotrec stride (shorts), 16B aligned
#define CG 2                 // column groups for nce
#define TPG 30               // col tiles per group
#define CLINES 64            // lines per gather chunk
#define NCHUNK 15            // ceil(950/64) worst case

typedef short bf16x8 __attribute__((ext_vector_type(8)));
typedef float f32x4  __attribute__((ext_vector_type(4)));

static __device__ __forceinline__ unsigned short f2bf(float f) {
    unsigned int u = __float_as_uint(f);
    unsigned int r = (u + 0x7fffu + ((u >> 16) & 1u)) >> 16;   // RNE
    return (unsigned short)r;
}
static __device__ __forceinline__ float bf2f(unsigned short h) {
    return __uint_as_float(((unsigned int)h) << 16);
}
__device__ __forceinline__ void lse_merge(float& m, float& s, float m2, float s2) {
    float nm = fmaxf(m, m2);
    float d1 = m - nm;  d1 = (d1 < 0.f) ? d1 : 0.f;   // clamp kills NaN from inf-inf
    float d2 = m2 - nm; d2 = (d2 < 0.f) ? d2 : 0.f;
    s = s * __expf(d1) + s2 * __expf(d2);
    m = nm;
}

// ---------------- setup ----------------
__global__ __launch_bounds__(256)
void init_kernel(long long* __restrict__ map8, unsigned int* __restrict__ bitmap,
                 int* __restrict__ counts) {
    int i = blockIdx.x * 256 + threadIdx.x;       // 64 blocks: BB*HW shorts as 8B
    map8[i] = -1LL;
    if (blockIdx.x == 0) {
        if (threadIdx.x < BB * 32) bitmap[threadIdx.x] = 0u;
        if (threadIdx.x < BB) counts[threadIdx.x] = 0;
    }
}

__global__ __launch_bounds__(256)
void scatter_kernel(const int* __restrict__ sidx, short* __restrict__ map,
                    unsigned int* __restrict__ bitmap) {
    int i = blockIdx.x * 256 + threadIdx.x;
    if (i >= BB * PP) return;
    int b = i / PP, p = i - b * PP;
    int pix = sidx[i];
    map[(size_t)b * HW + pix] = (short)p;
    atomicOr(&bitmap[b * 32 + (pix >> 9)], 1u << ((pix >> 4) & 31));
}

// compact sorted used-line list + per-line 16-pixel slot records
__global__ __launch_bounds__(1024)
void listslot_kernel(const unsigned int* __restrict__ bitmap, const short* __restrict__ map,
                     unsigned short* __restrict__ list, short* __restrict__ slotrec,
                     int* __restrict__ counts) {
    __shared__ unsigned short lls[NLINES];
    __shared__ int wbase[16];
    __shared__ int Ls;
    int b = blockIdx.x;
    int tid = threadIdx.x;                        // tid == line number
    int lane = tid & 63, wv = tid >> 6;
    unsigned int word = bitmap[b * 32 + (tid >> 5)];
    int bit = (word >> (tid & 31)) & 1;
    unsigned long long mask = __ballot(bit);
    int rank = __popcll(mask & ((1ull << lane) - 1ull));
    if (lane == 0) wbase[wv] = __popcll(mask);
    __syncthreads();
    if (tid == 0) {
        int acc = 0;
        for (int w2 = 0; w2 < 16; ++w2) { int t = wbase[w2]; wbase[w2] = acc; acc += t; }
        counts[b] = acc; Ls = acc;
    }
    __syncthreads();
    if (bit) {
        int pos = wbase[wv] + rank;
        lls[pos] = (unsigned short)tid;
        list[b * NLINES + pos] = (unsigned short)tid;
    }
    __syncthreads();
    int L = Ls;
    for (int idx = tid; idx < L * 16; idx += 1024) {
        int li = idx >> 4, px = idx & 15;
        int ln = lls[li];
        slotrec[(size_t)b * SRSTRIDE + idx] = map[(size_t)b * HW + ln * 16 + px];
    }
}

// ---------------- gather: line-granular float4 streaming, no LDS, big grid ----------------
__global__ __launch_bounds__(256)
void gather_kernel(const float* __restrict__ fq, const float* __restrict__ fk,
                   const unsigned short* __restrict__ list, const short* __restrict__ slotrec,
                   const int* __restrict__ counts,
                   unsigned short* __restrict__ xqh, unsigned short* __restrict__ xql,
                   unsigned short* __restrict__ xkh, unsigned short* __restrict__ xkl) {
    int b = blockIdx.z;
    int chunk = blockIdx.y;
    int id = blockIdx.x;                  // tensor(1b) x channel-group(5b)
    int L = counts[b];
    if (chunk * CLINES >= L) return;

    int tensor = id >> 5;
    int c0 = (id & 31) * 8;
    const float* src = (tensor ? fk : fq) + ((size_t)b * CC + c0) * HW;
    unsigned short* oh = (tensor ? xkh : xqh);
    unsigned short* ol = (tensor ? xkl : xql);

    int tid = threadIdx.x;
    int lq = tid & 3;                     // 16B quarter within the 64B line
    int li = tid >> 2;                    // line slot within chunk (0..63)
    int i = chunk * CLINES + li;
    bool ok = (i < L);
    int ic = ok ? i : (L - 1);

    int line = list[b * NLINES + ic];
    const float* sb = src + line * 16 + lq * 4;
    float4 v[8];
#pragma unroll
    for (int ch = 0; ch < 8; ++ch)
        v[ch] = *(const float4*)(sb + ch * HW);   // 8 independent 16B loads in flight

    unsigned long long sl =
        *(const unsigned long long*)(slotrec + (size_t)b * SRSTRIDE + ic * 16 + lq * 4);
    if (!ok) return;

#pragma unroll
    for (int j = 0; j < 4; ++j) {
        int slot = (int)(short)((sl >> (16 * j)) & 0xffffu);
        if (slot >= 0) {
            unsigned int hw_[4], lw_[4];
#pragma unroll
            for (int p = 0; p < 4; ++p) {
                float a  = ((const float*)&v[2 * p])[j];
                float c_ = ((const float*)&v[2 * p + 1])[j];
                unsigned short ha = f2bf(a), hb = f2bf(c_);
                float la = a  - bf2f(ha);
                float lb = c_ - bf2f(hb);
                hw_[p] = (unsigned int)ha | ((unsigned int)hb << 16);
                lw_[p] = (unsigned int)f2bf(la) | ((unsigned int)f2bf(lb) << 16);
            }
            size_t dst = ((size_t)b * PP + slot) * CC + c0;
            *(int4*)(oh + dst) = make_int4(hw_[0], hw_[1], hw_[2], hw_[3]);
            *(int4*)(ol + dst) = make_int4(lw_[0], lw_[1], lw_[2], lw_[3]);
        }
    }
}

// ---------------- MFMA Gram + masked online-LSE, double-buffered B, 2-way col split ----------------
#define LOADT(BUF, TT) do {                                                     \
    int n0_ = (TT) * 16;                                                        \
    int brow_ = n0_ + lr; if (brow_ > PP - 1) brow_ = PP - 1;                   \
    size_t bbase_ = ((size_t)b * PP + brow_) * CC + lg * 8;                     \
    _Pragma("unroll")                                                           \
    for (int kt = 0; kt < 8; ++kt) {                                            \
        Bh##BUF[kt] = *(const bf16x8*)(xkh + bbase_ + kt * 32);                 \
        Bl##BUF[kt] = *(const bf16x8*)(xkl + bbase_ + kt * 32);                 \
    }                                                                           \
} while (0)

#define COMPUTE(BUF, TT) do {                                                   \
    int n0_ = (TT) * 16;                                                        \
    f32x4 acc = {0.f, 0.f, 0.f, 0.f};                                           \
    _Pragma("unroll")                                                           \
    for (int kt = 0; kt < 8; ++kt) {                                            \
        acc = __builtin_amdgcn_mfma_f32_16x16x32_bf16(Ah[kt], Bh##BUF[kt], acc, 0, 0, 0); \
        acc = __builtin_amdgcn_mfma_f32_16x16x32_bf16(Ah[kt], Bl##BUF[kt], acc, 0, 0, 0); \
        acc = __builtin_amdgcn_mfma_f32_16x16x32_bf16(Al[kt], Bh##BUF[kt], acc, 0, 0, 0); \
    }                                                                           \
    int col = n0_ + lr;                                                         \
    bool colok = (col < PP);                                                    \
    int ccls = col / NV;                                                        \
    _Pragma("unroll")                                                           \
    for (int j = 0; j < 4; ++j) {                                               \
        float x = acc[j] * INV_T;                                               \
        int row = r0 + lg * 4 + j;                                              \
        if (rok[j] && col == row) pos[(size_t)b * PP + row] = x;                \
        bool okm = rok[j] && colok && ((ccls != rcls[j]) || (col == row));      \
        if (okm) {                                                              \
            if (x > m[j]) { s[j] = s[j] * __expf(m[j] - x) + 1.f; m[j] = x; }   \
            else          { s[j] += __expf(x - m[j]); }                         \
        }                                                                       \
    }                                                                           \
} while (0)

__global__ __launch_bounds__(512)
void nce_mfma(const unsigned short* __restrict__ xqh, const unsigned short* __restrict__ xql,
              const unsigned short* __restrict__ xkh, const unsigned short* __restrict__ xkl,
              float* __restrict__ pos, float* __restrict__ pm, float* __restrict__ ps) {
    __shared__ float red_m[8][16];
    __shared__ float red_s[8][16];

    int b  = blockIdx.z;
    int cg = blockIdx.y;
    int r0 = blockIdx.x * 16;
    int tid = threadIdx.x;
    int w = tid >> 6, l = tid & 63;
    int lr = l & 15, lg = l >> 4;

    int arow = r0 + lr; if (arow > PP - 1) arow = PP - 1;
    size_t abase = ((size_t)b * PP + arow) * CC + lg * 8;
    bf16x8 Ah[8], Al[8];
#pragma unroll
    for (int kt = 0; kt < 8; ++kt) {
        Ah[kt] = *(const bf16x8*)(xqh + abase + kt * 32);
        Al[kt] = *(const bf16x8*)(xql + abase + kt * 32);
    }

    int   rcls[4]; bool rok[4];
    float m[4], s[4];
#pragma unroll
    for (int j = 0; j < 4; ++j) {
        int row = r0 + lg * 4 + j;
        rok[j] = (row < PP);
        rcls[j] = row / NV;
        m[j] = -INFINITY; s[j] = 0.f;
    }

    bf16x8 BhA[8], BlA[8], BhB[8], BlB[8];
    int tt = w;
    LOADT(A, cg * TPG + tt);
#pragma unroll
    for (int half = 0; half < 2; ++half) {
        if (tt + 8 < TPG) LOADT(B, cg * TPG + tt + 8);
        COMPUTE(A, cg * TPG + tt);
        tt += 8;
        if (tt >= TPG) break;
        if (tt + 8 < TPG) LOADT(A, cg * TPG + tt + 8);
        COMPUTE(B, cg * TPG + tt);
        tt += 8;
        if (tt >= TPG) break;
    }

#pragma unroll
    for (int j = 0; j < 4; ++j) {
#pragma unroll
        for (int off = 1; off <= 8; off <<= 1) {
            float m2 = __shfl_xor(m[j], off, 64);
            float s2 = __shfl_xor(s[j], off, 64);
            lse_merge(m[j], s[j], m2, s2);
        }
    }
    if (lr == 0) {
#pragma unroll
        for (int j = 0; j < 4; ++j) { red_m[w][lg * 4 + j] = m[j]; red_s[w][lg * 4 + j] = s[j]; }
    }
    __syncthreads();

    if (tid < 16) {
        int row = r0 + tid;
        if (row < PP) {
            float mm = red_m[0][tid], ss = red_s[0][tid];
#pragma unroll
            for (int ww = 1; ww < 8; ++ww) lse_merge(mm, ss, red_m[ww][tid], red_s[ww][tid]);
            size_t o = ((size_t)b * CG + cg) * (RT * 16) + row;
            pm[o] = mm; ps[o] = ss;
        }
    }
}

__global__ __launch_bounds__(256)
void finalize_kernel(const float* __restrict__ pm, const float* __restrict__ ps,
                     const float* __restrict__ pos, float* __restrict__ out) {
    int i = blockIdx.x * 256 + threadIdx.x;
    if (i >= BB * PP) return;
    int b = i / PP, row = i - b * PP;
    float m = -INFINITY, s = 0.f;
#pragma unroll
    for (int g = 0; g < CG; ++g) {
        size_t o = ((size_t)b * CG + g) * (RT * 16) + row;
        lse_merge(m, s, pm[o], ps[o]);
    }
    out[i] = m + logf(s) - pos[i];
}

extern "C" void kernel_launch(void* const* d_in, const int* in_sizes, int n_in,
                              void* d_out, int out_size, void* d_ws, size_t ws_size,
                              hipStream_t stream) {
    const float* fq   = (const float*)d_in[0];
    const float* fk   = (const float*)d_in[1];
    const int*   sidx = (const int*)d_in[2];
    float* outp = (float*)d_out;

    char* p = (char*)d_ws;
    unsigned short* xqh = (unsigned short*)p; p += PLANE * 2;
    unsigned short* xql = (unsigned short*)p; p += PLANE * 2;
    unsigned short* xkh = (unsigned short*)p; p += PLANE * 2;
    unsigned short* xkl = (unsigned short*)p; p += PLANE * 2;
    short*          map = (short*)p;          p += (size_t)BB * HW * 2;
    short*      slotrec = (short*)p;          p += (size_t)BB * SRSTRIDE * 2;
    unsigned short* list = (unsigned short*)p; p += BB * NLINES * 2;
    unsigned int* bitmap = (unsigned int*)p;  p += BB * 32 * 4;
    int*         counts = (int*)p;            p += BB * 4;
    float*          pos = (float*)p;          p += (size_t)BB * PP * 4;
    float*           pm = (float*)p;          p += (size_t)BB * CG * RT * 16 * 4;
    float*           ps = (float*)p;

    init_kernel<<<dim3(64), 256, 0, stream>>>((long long*)map, bitmap, counts);
    scatter_kernel<<<dim3((BB * PP + 255) / 256), 256, 0, stream>>>(sidx, map, bitmap);
    listslot_kernel<<<dim3(BB), 1024, 0, stream>>>(bitmap, map, list, slotrec, counts);
    gather_kernel<<<dim3(64, NCHUNK, BB), 256, 0, stream>>>(fq, fk, list, slotrec, counts,
                                                            xqh, xql, xkh, xkl);
    nce_mfma<<<dim3(RT, CG, BB), 512, 0, stream>>>(xqh, xql, xkh, xkl, pos, pm, ps);
    finalize_kernel<<<dim3((BB * PP + 255) / 256), 256, 0, stream>>>(pm, ps, pos, outp);
}

// Round 6
// 76.492 us; speedup vs baseline: 1.0748x; 1.0748x over previous
//
#include <hip/hip_runtime.h>
#include <math.h>

#define BB 4
#define CC 256
#define HW (128*128)
#define NC 19
#define NV 50
#define PP 950
#define INV_T (1.0f/0.07f)
#define PLANE ((size_t)BB * PP * CC)
#define NSC 20               // col supergroups of 48 (960)
#define NRQ 30               // row groups of 32 (960)

typedef short bf16x8 __attribute__((ext_vector_type(8)));
typedef float f32x4  __attribute__((ext_vector_type(4)));

static __device__ __forceinline__ unsigned short f2bf(float f) {
    unsigned int u = __float_as_uint(f);
    unsigned int r = (u + 0x7fffu + ((u >> 16) & 1u)) >> 16;   // RNE
    return (unsigned short)r;
}
static __device__ __forceinline__ float bf2f(unsigned short h) {
    return __uint_as_float(((unsigned int)h) << 16);
}
__device__ __forceinline__ void lse_merge(float& m, float& s, float m2, float s2) {
    float nm = fmaxf(m, m2);
    float e1 = __expf(m - nm);          // finite sentinels (-1e30), no NaN
    float e2 = __expf(m2 - nm);
    s = s * e1 + s2 * e2;
    m = nm;
}

// ---------------- map build: clear + scatter, one block per b ----------------
__global__ __launch_bounds__(1024)
void mapbuild_kernel(const int* __restrict__ sidx, short* __restrict__ map) {
    int b = blockIdx.x;
    int tid = threadIdx.x;
    int4* m4 = (int4*)(map + (size_t)b * HW);
    int4 mone = make_int4(-1, -1, -1, -1);
    m4[tid] = mone;
    m4[tid + 1024] = mone;
    __syncthreads();
    if (tid < PP) {
        int pix = sidx[b * PP + tid];
        map[(size_t)b * HW + pix] = (short)tid;
    }
}

// ---------------- streaming gather: read ALL pixels coalesced, keep 5.8% ----------------
__global__ __launch_bounds__(256)
void gather_kernel(const float* __restrict__ fq, const float* __restrict__ fk,
                   const short* __restrict__ map,
                   unsigned short* __restrict__ xqh, unsigned short* __restrict__ xql,
                   unsigned short* __restrict__ xkh, unsigned short* __restrict__ xkl) {
    int x = blockIdx.x;                 // 4096 = b(2b) t(1b) cg(3b) chunk(6b)
    int chunk  = x & 63;
    int cg     = (x >> 6) & 7;
    int tensor = (x >> 9) & 1;
    int b      = x >> 10;
    int px0 = chunk * 256;

    __shared__ short mp[256];
    int tid = threadIdx.x;
    if (tid < 32)
        ((int4*)mp)[tid] = ((const int4*)(map + (size_t)b * HW + px0))[tid];
    __syncthreads();

    const float* f = tensor ? fk : fq;
    unsigned short* oh = tensor ? xkh : xqh;
    unsigned short* ol = tensor ? xkl : xql;

    int lp  = tid & 15;                 // 16 lanes cover 256B contiguous per row
    int chl = tid >> 4;                 // 0..15
    int ch0 = cg * 32 + chl;
    int ch1 = ch0 + 16;
    const float* s0 = f + ((size_t)b * CC + ch0) * HW + px0;
    const float* s1 = f + ((size_t)b * CC + ch1) * HW + px0;

    float4 v[8];
#pragma unroll
    for (int i = 0; i < 4; ++i) v[i]     = *(const float4*)(s0 + (i * 16 + lp) * 4);
#pragma unroll
    for (int i = 0; i < 4; ++i) v[4 + i] = *(const float4*)(s1 + (i * 16 + lp) * 4);

#pragma unroll
    for (int k = 0; k < 8; ++k) {
        int i  = k & 3;
        int ch = (k < 4) ? ch0 : ch1;
#pragma unroll
        for (int e = 0; e < 4; ++e) {
            int px = (i * 16 + lp) * 4 + e;
            int slot = mp[px];
            if (slot >= 0) {
                float val = ((const float*)&v[k])[e];
                unsigned short h = f2bf(val);
                size_t dst = ((size_t)b * PP + slot) * CC + ch;
                oh[dst] = h;
                ol[dst] = f2bf(val - bf2f(h));
            }
        }
    }
}

// ---------------- MFMA Gram: wave = 32 rows x 48 cols, reg-dbuf K phases ----------------
#define LOADB(BH, BL, KT) do {                                                  \
    BH[0] = *(const bf16x8*)(xkh + bb0 + (KT) * 32);                            \
    BH[1] = *(const bf16x8*)(xkh + bb1 + (KT) * 32);                            \
    BH[2] = *(const bf16x8*)(xkh + bb2 + (KT) * 32);                            \
    BL[0] = *(const bf16x8*)(xkl + bb0 + (KT) * 32);                            \
    BL[1] = *(const bf16x8*)(xkl + bb1 + (KT) * 32);                            \
    BL[2] = *(const bf16x8*)(xkl + bb2 + (KT) * 32);                            \
} while (0)

#define MF(ACC, AF, BF) ACC = __builtin_amdgcn_mfma_f32_16x16x32_bf16(AF, BF, ACC, 0, 0, 0)

#define COMPK(BH, BL, KT) do {                                                  \
    MF(acc00, Ah0[KT], BH[0]); MF(acc10, Ah1[KT], BH[0]);                       \
    MF(acc01, Ah0[KT], BH[1]); MF(acc11, Ah1[KT], BH[1]);                       \
    MF(acc02, Ah0[KT], BH[2]); MF(acc12, Ah1[KT], BH[2]);                       \
    MF(acc00, Al0[KT], BH[0]); MF(acc10, Al1[KT], BH[0]);                       \
    MF(acc01, Al0[KT], BH[1]); MF(acc11, Al1[KT], BH[1]);                       \
    MF(acc02, Al0[KT], BH[2]); MF(acc12, Al1[KT], BH[2]);                       \
    MF(acc00, Ah0[KT], BL[0]); MF(acc10, Ah1[KT], BL[0]);                       \
    MF(acc01, Ah0[KT], BL[1]); MF(acc11, Ah1[KT], BL[1]);                       \
    MF(acc02, Ah0[KT], BL[2]); MF(acc12, Ah1[KT], BL[2]);                       \
} while (0)

#define ONLINE(M, S, XV, OK) do {                                               \
    float xm_ = (OK) ? (XV) : -1e30f;                                           \
    float nm_ = fmaxf(M, xm_);                                                  \
    float e1_ = __expf((M) - nm_);                                              \
    float e2_ = (OK) ? __expf((XV) - nm_) : 0.f;                                \
    S = (S) * e1_ + e2_; M = nm_;                                               \
} while (0)

#define EPIROW(A0, A1, A2, ROWBASE) do {                                        \
    _Pragma("unroll")                                                           \
    for (int jj = 0; jj < 4; ++jj) {                                            \
        int row = (ROWBASE) + lg * 4 + jj;                                      \
        bool rowok = row < PP;                                                  \
        int rcls = row / NV;                                                    \
        float m = -1e30f, s = 0.f;                                              \
        {   float xv = (A0)[jj] * INV_T;                                        \
            bool ok = rowok && c0ok && ((ccls0 != rcls) || (col0 == row));      \
            if (rowok && col0 == row) pos[(size_t)b * 960 + row] = xv;          \
            ONLINE(m, s, xv, ok); }                                             \
        {   float xv = (A1)[jj] * INV_T;                                        \
            bool ok = rowok && c1ok && ((ccls1 != rcls) || (col1 == row));      \
            if (rowok && col1 == row) pos[(size_t)b * 960 + row] = xv;          \
            ONLINE(m, s, xv, ok); }                                             \
        {   float xv = (A2)[jj] * INV_T;                                        \
            bool ok = rowok && c2ok && ((ccls2 != rcls) || (col2 == row));      \
            if (rowok && col2 == row) pos[(size_t)b * 960 + row] = xv;          \
            ONLINE(m, s, xv, ok); }                                             \
        _Pragma("unroll")                                                       \
        for (int off = 1; off < 16; off <<= 1) {                                \
            float m2 = __shfl_xor(m, off, 64);                                  \
            float s2 = __shfl_xor(s, off, 64);                                  \
            lse_merge(m, s, m2, s2);                                            \
        }                                                                       \
        if (lr == 0) {                                                          \
            pm[((size_t)b * NSC + sc) * 960 + row] = m;                         \
            ps[((size_t)b * NSC + sc) * 960 + row] = s;                         \
        }                                                                       \
    }                                                                           \
} while (0)

__global__ __launch_bounds__(256, 2)
void nce_mfma(const unsigned short* __restrict__ xqh, const unsigned short* __restrict__ xql,
              const unsigned short* __restrict__ xkh, const unsigned short* __restrict__ xkl,
              float* __restrict__ pos, float* __restrict__ pm, float* __restrict__ ps) {
    int bid = blockIdx.x;               // 600 blocks; b pinned to XCD pairs via bid&7
    int xcd = bid & 7;
    int b = xcd >> 1;
    int j = ((bid >> 3) << 1) + (xcd & 1);     // 0..149
    int w = threadIdx.x >> 6, l = threadIdx.x & 63;
    int jw = j * 4 + w;                 // 0..599
    int rq = jw % NRQ;                  // row group (32 rows)
    int sc = jw / NRQ;                  // col supergroup (48 cols)
    int lr = l & 15, lg = l >> 4;

    // ---- A: 32 rows (2 tiles) x K=256, hi+lo in registers ----
    int ar0 = rq * 32 + lr;
    int ar1 = ar0 + 16;
    int ar0c = ar0 < PP ? ar0 : PP - 1;
    int ar1c = ar1 < PP ? ar1 : PP - 1;
    size_t a0 = ((size_t)b * PP + ar0c) * CC + lg * 8;
    size_t a1 = ((size_t)b * PP + ar1c) * CC + lg * 8;
    bf16x8 Ah0[8], Al0[8], Ah1[8], Al1[8];
#pragma unroll
    for (int kt = 0; kt < 8; ++kt) {
        Ah0[kt] = *(const bf16x8*)(xqh + a0 + kt * 32);
        Al0[kt] = *(const bf16x8*)(xql + a0 + kt * 32);
        Ah1[kt] = *(const bf16x8*)(xqh + a1 + kt * 32);
        Al1[kt] = *(const bf16x8*)(xql + a1 + kt * 32);
    }

    // ---- B bases: 3 col tiles ----
    int c0i = sc * 48;
    int col0 = c0i + lr, col1 = col0 + 16, col2 = col0 + 32;
    int b0c = col0 < PP ? col0 : PP - 1;
    int b1c = col1 < PP ? col1 : PP - 1;
    int b2c = col2 < PP ? col2 : PP - 1;
    size_t bb0 = ((size_t)b * PP + b0c) * CC + lg * 8;
    size_t bb1 = ((size_t)b * PP + b1c) * CC + lg * 8;
    size_t bb2 = ((size_t)b * PP + b2c) * CC + lg * 8;
    bool c0ok = col0 < PP, c1ok = col1 < PP, c2ok = col2 < PP;
    int ccls0 = col0 / NV, ccls1 = col1 / NV, ccls2 = col2 / NV;

    f32x4 acc00 = {0.f,0.f,0.f,0.f}, acc01 = acc00, acc02 = acc00;
    f32x4 acc10 = acc00, acc11 = acc00, acc12 = acc00;

    bf16x8 BhA[3], BlA[3], BhB[3], BlB[3];
    LOADB(BhA, BlA, 0);
    LOADB(BhB, BlB, 1); COMPK(BhA, BlA, 0);
    LOADB(BhA, BlA, 2); COMPK(BhB, BlB, 1);
    LOADB(BhB, BlB, 3); COMPK(BhA, BlA, 2);
    LOADB(BhA, BlA, 4); COMPK(BhB, BlB, 3);
    LOADB(BhB, BlB, 5); COMPK(BhA, BlA, 4);
    LOADB(BhA, BlA, 6); COMPK(BhB, BlB, 5);
    LOADB(BhB, BlB, 7); COMPK(BhA, BlA, 6);
    COMPK(BhB, BlB, 7);

    // ---- masked online-LSE + 16-lane butterfly, partials to pm/ps ----
    EPIROW(acc00, acc01, acc02, rq * 32);
    EPIROW(acc10, acc11, acc12, rq * 32 + 16);
}

__global__ __launch_bounds__(256)
void finalize_kernel(const float* __restrict__ pm, const float* __restrict__ ps,
                     const float* __restrict__ pos, float* __restrict__ out) {
    int i = blockIdx.x * 256 + threadIdx.x;
    if (i >= BB * PP) return;
    int b = i / PP, row = i - b * PP;
    float m = -1e30f, s = 0.f;
#pragma unroll
    for (int g = 0; g < NSC; ++g) {
        size_t o = ((size_t)b * NSC + g) * 960 + row;
        lse_merge(m, s, pm[o], ps[o]);
    }
    out[i] = m + logf(s) - pos[(size_t)b * 960 + row];
}

extern "C" void kernel_launch(void* const* d_in, const int* in_sizes, int n_in,
                              void* d_out, int out_size, void* d_ws, size_t ws_size,
                              hipStream_t stream) {
    const float* fq   = (const float*)d_in[0];
    const float* fk   = (const float*)d_in[1];
    const int*   sidx = (const int*)d_in[2];
    float* outp = (float*)d_out;

    char* p = (char*)d_ws;
    unsigned short* xqh = (unsigned short*)p; p += PLANE * 2;
    unsigned short* xql = (unsigned short*)p; p += PLANE * 2;
    unsigned short* xkh = (unsigned short*)p; p += PLANE * 2;
    unsigned short* xkl = (unsigned short*)p; p += PLANE * 2;
    short*          map = (short*)p;          p += (size_t)BB * HW * 2;
    float*          pos = (float*)p;          p += (size_t)BB * 960 * 4;
    float*           pm = (float*)p;          p += (size_t)BB * NSC * 960 * 4;
    float*           ps = (float*)p;

    mapbuild_kernel<<<dim3(BB), 1024, 0, stream>>>(sidx, map);
    gather_kernel<<<dim3(4096), 256, 0, stream>>>(fq, fk, map, xqh, xql, xkh, xkl);
    nce_mfma<<<dim3(600), 256, 0, stream>>>(xqh, xql, xkh, xkl, pos, pm, ps);
    finalize_kernel<<<dim3((BB * PP + 255) / 256), 256, 0, stream>>>(pm, ps, pos, outp);
}

// Round 7
// 52.366 us; speedup vs baseline: 1.5699x; 1.4607x over previous
//
#include <hip/hip_runtime.h>
#include <math.h>

#define BB 4
#define CC 256
#define HW (128*128)
#define NC 19
#define NV 50
#define PP 950
#define INV_T (1.0f/0.07f)
#define PLANE ((size_t)BB * PP * CC)
#define NCG 8                // col groups of 128
#define LDSP 40              // padded halves per col (32 k + 8 pad) -> 80 B

typedef short bf16x8 __attribute__((ext_vector_type(8)));
typedef float f32x4  __attribute__((ext_vector_type(4)));

static __device__ __forceinline__ unsigned short f2bf(float f) {
    unsigned int u = __float_as_uint(f);
    unsigned int r = (u + 0x7fffu + ((u >> 16) & 1u)) >> 16;   // RNE
    return (unsigned short)r;
}
static __device__ __forceinline__ float bf2f(unsigned short h) {
    return __uint_as_float(((unsigned int)h) << 16);
}
__device__ __forceinline__ void lse_merge(float& m, float& s, float m2, float s2) {
    float nm = fmaxf(m, m2);
    float e1 = __expf(m - nm);          // finite sentinels (-1e30), no NaN
    float e2 = __expf(m2 - nm);
    s = s * e1 + s2 * e2;
    m = nm;
}

// ---------------- map build: clear + scatter, one block per b ----------------
__global__ __launch_bounds__(1024)
void mapbuild_kernel(const int* __restrict__ sidx, short* __restrict__ map) {
    int b = blockIdx.x;
    int tid = threadIdx.x;
    int4* m4 = (int4*)(map + (size_t)b * HW);
    int4 mone = make_int4(-1, -1, -1, -1);
    m4[tid] = mone;
    m4[tid + 1024] = mone;
    __syncthreads();
    if (tid < PP) {
        int pix = sidx[b * PP + tid];
        map[(size_t)b * HW + pix] = (short)tid;
    }
}

// ---------------- streaming gather: read ALL pixels coalesced, keep 5.8% ----------------
__global__ __launch_bounds__(256)
void gather_kernel(const float* __restrict__ fq, const float* __restrict__ fk,
                   const short* __restrict__ map,
                   unsigned short* __restrict__ xqh, unsigned short* __restrict__ xql,
                   unsigned short* __restrict__ xkh, unsigned short* __restrict__ xkl) {
    int x = blockIdx.x;                 // 4096 = b(2b) t(1b) cg(3b) chunk(6b)
    int chunk  = x & 63;
    int cg     = (x >> 6) & 7;
    int tensor = (x >> 9) & 1;
    int b      = x >> 10;
    int px0 = chunk * 256;

    __shared__ short mp[256];
    int tid = threadIdx.x;
    if (tid < 32)
        ((int4*)mp)[tid] = ((const int4*)(map + (size_t)b * HW + px0))[tid];
    __syncthreads();

    const float* f = tensor ? fk : fq;
    unsigned short* oh = tensor ? xkh : xqh;
    unsigned short* ol = tensor ? xkl : xql;

    int lp  = tid & 15;                 // 16 lanes cover 256B contiguous per row
    int chl = tid >> 4;                 // 0..15
    int ch0 = cg * 32 + chl;
    int ch1 = ch0 + 16;
    const float* s0 = f + ((size_t)b * CC + ch0) * HW + px0;
    const float* s1 = f + ((size_t)b * CC + ch1) * HW + px0;

    float4 v[8];
#pragma unroll
    for (int i = 0; i < 4; ++i) v[i]     = *(const float4*)(s0 + (i * 16 + lp) * 4);
#pragma unroll
    for (int i = 0; i < 4; ++i) v[4 + i] = *(const float4*)(s1 + (i * 16 + lp) * 4);

#pragma unroll
    for (int k = 0; k < 8; ++k) {
        int i  = k & 3;
        int ch = (k < 4) ? ch0 : ch1;
#pragma unroll
        for (int e = 0; e < 4; ++e) {
            int px = (i * 16 + lp) * 4 + e;
            int slot = mp[px];
            if (slot >= 0) {
                float val = ((const float*)&v[k])[e];
                unsigned short h = f2bf(val);
                size_t dst = ((size_t)b * PP + slot) * CC + ch;
                oh[dst] = h;
                ol[dst] = f2bf(val - bf2f(h));
            }
        }
    }
}

// ---------------- nce: LDS-staged block GEMM 128x128, 8 waves, dbuf k-steps ----------------
#define MF(ACC, AF, BF) ACC = __builtin_amdgcn_mfma_f32_16x16x32_bf16(AF, BF, ACC, 0, 0, 0)

#define STEP(KT) do {                                                           \
    int4 rh_, rl_;                                                              \
    if ((KT) < 7) {                                                             \
        rh_ = *(const int4*)(xkh + stage_src + ((KT) + 1) * 32);                \
        rl_ = *(const int4*)(xkl + stage_src + ((KT) + 1) * 32);                \
    }                                                                           \
    const short* bbase_ = &bl[(KT) & 1][0][0] + lr * LDSP + lg * 8;             \
    _Pragma("unroll")                                                           \
    for (int ct = 0; ct < 8; ++ct) {                                            \
        const short* bp_ = bbase_ + ct * (16 * LDSP);                           \
        bf16x8 Bh_ = *(const bf16x8*)bp_;                                       \
        bf16x8 Bl_ = *(const bf16x8*)(bp_ + 128 * LDSP);                        \
        MF(acc[ct], Ah[KT], Bh_);                                               \
        MF(acc[ct], Al[KT], Bh_);                                               \
        MF(acc[ct], Ah[KT], Bl_);                                               \
    }                                                                           \
    if ((KT) < 7) {                                                             \
        *(int4*)&bl[((KT) + 1) & 1][0][stage_dst] = rh_;                        \
        *(int4*)&bl[((KT) + 1) & 1][1][stage_dst] = rl_;                        \
        __syncthreads();                                                        \
    }                                                                           \
} while (0)

__global__ __launch_bounds__(512)
void nce_mfma(const unsigned short* __restrict__ xqh, const unsigned short* __restrict__ xql,
              const unsigned short* __restrict__ xkh, const unsigned short* __restrict__ xkl,
              float* __restrict__ pos, float* __restrict__ pm, float* __restrict__ ps) {
    __shared__ short bl[2][2][128 * LDSP];      // 40 KB: [dbuf][plane][col*LDSP+k]

    int cg = blockIdx.x;                        // col group (128 cols)
    int rb = blockIdx.y;                        // row block (128 rows)
    int b  = blockIdx.z;
    int tid = threadIdx.x;
    int w = tid >> 6, l = tid & 63;
    int lr = l & 15, lg = l >> 4;

    // ---- staging assignment: thread -> (col, 16B quarter) ----
    int uc = tid >> 2, uq = tid & 3;
    int gcol = cg * 128 + uc; if (gcol > PP - 1) gcol = PP - 1;
    size_t stage_src = ((size_t)b * PP + gcol) * CC + uq * 8;
    int stage_dst = uc * LDSP + uq * 8;

    // ---- A: 16 rows x K=256 hi+lo in registers ----
    int arow = rb * 128 + w * 16 + lr; if (arow > PP - 1) arow = PP - 1;
    size_t abase = ((size_t)b * PP + arow) * CC + lg * 8;
    bf16x8 Ah[8], Al[8];
#pragma unroll
    for (int kt = 0; kt < 8; ++kt) {
        Ah[kt] = *(const bf16x8*)(xqh + abase + kt * 32);
        Al[kt] = *(const bf16x8*)(xql + abase + kt * 32);
    }

    // prologue: stage k-chunk 0 into buf 0
    {
        int4 rh = *(const int4*)(xkh + stage_src);
        int4 rl = *(const int4*)(xkl + stage_src);
        *(int4*)&bl[0][0][stage_dst] = rh;
        *(int4*)&bl[0][1][stage_dst] = rl;
    }
    __syncthreads();

    f32x4 acc[8];
#pragma unroll
    for (int ct = 0; ct < 8; ++ct) acc[ct] = (f32x4){0.f, 0.f, 0.f, 0.f};

    STEP(0); STEP(1); STEP(2); STEP(3);
    STEP(4); STEP(5); STEP(6); STEP(7);

    // ---- masked online-LSE epilogue ----
#pragma unroll
    for (int j = 0; j < 4; ++j) {
        int row = rb * 128 + w * 16 + lg * 4 + j;
        bool rowok = row < PP;
        int rcls = row / NV;
        float m = -1e30f, s = 0.f;
#pragma unroll
        for (int ct = 0; ct < 8; ++ct) {
            int col = cg * 128 + ct * 16 + lr;
            bool colok = col < PP;
            int ccls = col / NV;
            float x = acc[ct][j] * INV_T;
            bool ok = rowok && colok && ((ccls != rcls) || (col == row));
            if (rowok && col == row) pos[(size_t)b * 960 + row] = x;
            float xm = ok ? x : -1e30f;
            float nm = fmaxf(m, xm);
            float e1 = __expf(m - nm);
            float e2 = ok ? __expf(x - nm) : 0.f;
            s = s * e1 + e2; m = nm;
        }
#pragma unroll
        for (int off = 1; off <= 8; off <<= 1) {
            float m2 = __shfl_xor(m, off, 64);
            float s2 = __shfl_xor(s, off, 64);
            lse_merge(m, s, m2, s2);
        }
        if (lr == 0 && rowok) {
            pm[((size_t)b * NCG + cg) * 960 + row] = m;
            ps[((size_t)b * NCG + cg) * 960 + row] = s;
        }
    }
}

__global__ __launch_bounds__(256)
void finalize_kernel(const float* __restrict__ pm, const float* __restrict__ ps,
                     const float* __restrict__ pos, float* __restrict__ out) {
    int i = blockIdx.x * 256 + threadIdx.x;
    if (i >= BB * PP) return;
    int b = i / PP, row = i - b * PP;
    float m = -1e30f, s = 0.f;
#pragma unroll
    for (int g = 0; g < NCG; ++g) {
        size_t o = ((size_t)b * NCG + g) * 960 + row;
        lse_merge(m, s, pm[o], ps[o]);
    }
    out[i] = m + logf(s) - pos[(size_t)b * 960 + row];
}

extern "C" void kernel_launch(void* const* d_in, const int* in_sizes, int n_in,
                              void* d_out, int out_size, void* d_ws, size_t ws_size,
                              hipStream_t stream) {
    const float* fq   = (const float*)d_in[0];
    const float* fk   = (const float*)d_in[1];
    const int*   sidx = (const int*)d_in[2];
    float* outp = (float*)d_out;

    char* p = (char*)d_ws;
    unsigned short* xqh = (unsigned short*)p; p += PLANE * 2;
    unsigned short* xql = (unsigned short*)p; p += PLANE * 2;
    unsigned short* xkh = (unsigned short*)p; p += PLANE * 2;
    unsigned short* xkl = (unsigned short*)p; p += PLANE * 2;
    short*          map = (short*)p;          p += (size_t)BB * HW * 2;
    float*          pos = (float*)p;          p += (size_t)BB * 960 * 4;
    float*           pm = (float*)p;          p += (size_t)BB * NCG * 960 * 4;
    float*           ps = (float*)p;

    mapbuild_kernel<<<dim3(BB), 1024, 0, stream>>>(sidx, map);
    gather_kernel<<<dim3(4096), 256, 0, stream>>>(fq, fk, map, xqh, xql, xkh, xkl);
    nce_mfma<<<dim3(NCG, 8, BB), 512, 0, stream>>>(xqh, xql, xkh, xkl, pos, pm, ps);
    finalize_kernel<<<dim3((BB * PP + 255) / 256), 256, 0, stream>>>(pm, ps, pos, outp);
}

// Round 8
// 51.469 us; speedup vs baseline: 1.5973x; 1.0174x over previous
//
#include <hip/hip_runtime.h>
#include <math.h>

#define BB 4
#define CC 256
#define HW (128*128)
#define NC 19
#define NV 50
#define PP 950
#define INV_T (1.0f/0.07f)
#define PLANE ((size_t)BB * PP * CC)
#define NCG 8                // col groups of 128 (nce)
#define LDSP 40              // padded halves per col (32 k + 8 pad)
#define NCHK 64              // 256-px chunks per image
#define MAXE 64              // max used pixels per chunk (lambda=14.8, safe)

typedef short bf16x8 __attribute__((ext_vector_type(8)));
typedef float f32x4  __attribute__((ext_vector_type(4)));

static __device__ __forceinline__ unsigned short f2bf(float f) {
    unsigned int u = __float_as_uint(f);
    unsigned int r = (u + 0x7fffu + ((u >> 16) & 1u)) >> 16;   // RNE
    return (unsigned short)r;
}
static __device__ __forceinline__ float bf2f(unsigned short h) {
    return __uint_as_float(((unsigned int)h) << 16);
}
__device__ __forceinline__ void lse_merge(float& m, float& s, float m2, float s2) {
    float nm = fmaxf(m, m2);
    float e1 = __expf(m - nm);          // finite sentinels (-1e30), no NaN
    float e2 = __expf(m2 - nm);
    s = s * e1 + s2 * e2;
    m = nm;
}

// ---------------- mapbuild: per-(b,chunk) compacted (slot,px_local) lists ----------------
__global__ __launch_bounds__(1024)
void mapbuild_kernel(const int* __restrict__ sidx,
                     int* __restrict__ clist, int* __restrict__ ccnt) {
    __shared__ int lcnt[NCHK];
    __shared__ int lent[NCHK * MAXE];
    int b = blockIdx.x;
    int tid = threadIdx.x;
    if (tid < NCHK) lcnt[tid] = 0;
    __syncthreads();
    if (tid < PP) {
        int pix = sidx[b * PP + tid];
        int chunk = pix >> 8, pl = pix & 255;
        int pos = atomicAdd(&lcnt[chunk], 1);
        if (pos < MAXE) lent[chunk * MAXE + pos] = (tid << 8) | pl;
    }
    __syncthreads();
    if (tid < NCHK) {
        int c = lcnt[tid];
        ccnt[b * NCHK + tid] = c < MAXE ? c : MAXE;
    }
    for (int i = tid; i < NCHK * MAXE; i += 1024)
        clist[b * NCHK * MAXE + i] = lent[i];
}

// ---------------- streaming gather: coalesced read, LDS-routed wide writes ----------------
__global__ __launch_bounds__(256)
void gather_kernel(const float* __restrict__ fq, const float* __restrict__ fk,
                   const int* __restrict__ clist, const int* __restrict__ ccnt,
                   unsigned short* __restrict__ xqh, unsigned short* __restrict__ xql,
                   unsigned short* __restrict__ xkh, unsigned short* __restrict__ xkl) {
    __shared__ short pxmap[256];
    __shared__ short slotarr[MAXE];
    __shared__ short bufh[MAXE][32];
    __shared__ short bufl[MAXE][32];

    int x = blockIdx.x;                 // cg(3 hi) | b(2) | tensor(1) | chunk(6 lo)
    int chunk  = x & 63;
    int tensor = (x >> 6) & 1;
    int b      = (x >> 7) & 3;
    int cg     = x >> 9;
    int px0 = chunk * 256;

    int tid = threadIdx.x;
    int cnt = ccnt[b * NCHK + chunk];

    pxmap[tid] = -1;
    __syncthreads();
    if (tid < cnt) {
        int e = clist[(b * NCHK + chunk) * MAXE + tid];
        slotarr[tid] = (short)(e >> 8);
        pxmap[e & 255] = (short)tid;
    }
    __syncthreads();

    const float* f = tensor ? fk : fq;
    unsigned short* oh = tensor ? xkh : xqh;
    unsigned short* ol = tensor ? xkl : xql;

    int lp  = tid & 15;
    int chl = tid >> 4;                 // 0..15
    int ch0 = cg * 32 + chl;
    int ch1 = ch0 + 16;
    const float* s0 = f + ((size_t)b * CC + ch0) * HW + px0;
    const float* s1 = f + ((size_t)b * CC + ch1) * HW + px0;

    float4 v[8];
#pragma unroll
    for (int i = 0; i < 4; ++i) v[i]     = *(const float4*)(s0 + (i * 16 + lp) * 4);
#pragma unroll
    for (int i = 0; i < 4; ++i) v[4 + i] = *(const float4*)(s1 + (i * 16 + lp) * 4);

#pragma unroll
    for (int k = 0; k < 8; ++k) {
        int i = k & 3;
        int lch = (k < 4) ? chl : (chl + 16);
#pragma unroll
        for (int e = 0; e < 4; ++e) {
            int px = i * 64 + lp * 4 + e;
            int le = pxmap[px];
            if (le >= 0) {
                float val = ((const float*)&v[k])[e];
                unsigned short h = f2bf(val);
                bufh[le][lch] = (short)h;
                bufl[le][lch] = (short)f2bf(val - bf2f(h));
            }
        }
    }
    __syncthreads();

    // flush: (entry, plane, 16B quarter) -> 4-lane-coalesced 64B segments
#pragma unroll
    for (int rep = 0; rep < 2; ++rep) {
        int e = rep * 32 + (tid >> 3);
        int plane = (tid >> 2) & 1, q = tid & 3;
        if (e < cnt) {
            int slot = slotarr[e];
            size_t dst = ((size_t)b * PP + slot) * CC + cg * 32 + q * 8;
            const short* sp = (plane ? &bufl[e][0] : &bufh[e][0]) + q * 8;
            *(int4*)((plane ? ol : oh) + dst) = *(const int4*)sp;
        }
    }
}

// ---------------- nce: LDS-staged block GEMM 128x128, 8 waves, dbuf k-steps ----------------
#define MF(ACC, AF, BF) ACC = __builtin_amdgcn_mfma_f32_16x16x32_bf16(AF, BF, ACC, 0, 0, 0)

#define STEP(KT) do {                                                           \
    int4 rh_, rl_;                                                              \
    if ((KT) < 7) {                                                             \
        rh_ = *(const int4*)(xkh + stage_src + ((KT) + 1) * 32);                \
        rl_ = *(const int4*)(xkl + stage_src + ((KT) + 1) * 32);                \
    }                                                                           \
    const short* bbase_ = &bl[(KT) & 1][0][0] + lr * LDSP + lg * 8;             \
    _Pragma("unroll")                                                           \
    for (int ct = 0; ct < 8; ++ct) {                                            \
        const short* bp_ = bbase_ + ct * (16 * LDSP);                           \
        bf16x8 Bh_ = *(const bf16x8*)bp_;                                       \
        bf16x8 Bl_ = *(const bf16x8*)(bp_ + 128 * LDSP);                        \
        MF(acc[ct], Ah[KT], Bh_);                                               \
        MF(acc[ct], Al[KT], Bh_);                                               \
        MF(acc[ct], Ah[KT], Bl_);                                               \
    }                                                                           \
    if ((KT) < 7) {                                                             \
        *(int4*)&bl[((KT) + 1) & 1][0][stage_dst] = rh_;                        \
        *(int4*)&bl[((KT) + 1) & 1][1][stage_dst] = rl_;                        \
        __syncthreads();                                                        \
    }                                                                           \
} while (0)

__global__ __launch_bounds__(512)
void nce_mfma(const unsigned short* __restrict__ xqh, const unsigned short* __restrict__ xql,
              const unsigned short* __restrict__ xkh, const unsigned short* __restrict__ xkl,
              float* __restrict__ pos, float* __restrict__ pm, float* __restrict__ ps) {
    __shared__ short bl[2][2][128 * LDSP];      // 40 KB: [dbuf][plane][col*LDSP+k]

    int cg = blockIdx.x;                        // col group (128 cols)
    int rb = blockIdx.y;                        // row block (128 rows)
    int b  = blockIdx.z;
    int tid = threadIdx.x;
    int w = tid >> 6, l = tid & 63;
    int lr = l & 15, lg = l >> 4;

    int uc = tid >> 2, uq = tid & 3;
    int gcol = cg * 128 + uc; if (gcol > PP - 1) gcol = PP - 1;
    size_t stage_src = ((size_t)b * PP + gcol) * CC + uq * 8;
    int stage_dst = uc * LDSP + uq * 8;

    int arow = rb * 128 + w * 16 + lr; if (arow > PP - 1) arow = PP - 1;
    size_t abase = ((size_t)b * PP + arow) * CC + lg * 8;
    bf16x8 Ah[8], Al[8];
#pragma unroll
    for (int kt = 0; kt < 8; ++kt) {
        Ah[kt] = *(const bf16x8*)(xqh + abase + kt * 32);
        Al[kt] = *(const bf16x8*)(xql + abase + kt * 32);
    }

    {
        int4 rh = *(const int4*)(xkh + stage_src);
        int4 rl = *(const int4*)(xkl + stage_src);
        *(int4*)&bl[0][0][stage_dst] = rh;
        *(int4*)&bl[0][1][stage_dst] = rl;
    }
    __syncthreads();

    f32x4 acc[8];
#pragma unroll
    for (int ct = 0; ct < 8; ++ct) acc[ct] = (f32x4){0.f, 0.f, 0.f, 0.f};

    STEP(0); STEP(1); STEP(2); STEP(3);
    STEP(4); STEP(5); STEP(6); STEP(7);

#pragma unroll
    for (int j = 0; j < 4; ++j) {
        int row = rb * 128 + w * 16 + lg * 4 + j;
        bool rowok = row < PP;
        int rcls = row / NV;
        float m = -1e30f, s = 0.f;
#pragma unroll
        for (int ct = 0; ct < 8; ++ct) {
            int col = cg * 128 + ct * 16 + lr;
            bool colok = col < PP;
            int ccls = col / NV;
            float x = acc[ct][j] * INV_T;
            bool ok = rowok && colok && ((ccls != rcls) || (col == row));
            if (rowok && col == row) pos[(size_t)b * 960 + row] = x;
            float xm = ok ? x : -1e30f;
            float nm = fmaxf(m, xm);
            float e1 = __expf(m - nm);
            float e2 = ok ? __expf(x - nm) : 0.f;
            s = s * e1 + e2; m = nm;
        }
#pragma unroll
        for (int off = 1; off <= 8; off <<= 1) {
            float m2 = __shfl_xor(m, off, 64);
            float s2 = __shfl_xor(s, off, 64);
            lse_merge(m, s, m2, s2);
        }
        if (lr == 0 && rowok) {
            pm[((size_t)b * NCG + cg) * 960 + row] = m;
            ps[((size_t)b * NCG + cg) * 960 + row] = s;
        }
    }
}

__global__ __launch_bounds__(256)
void finalize_kernel(const float* __restrict__ pm, const float* __restrict__ ps,
                     const float* __restrict__ pos, float* __restrict__ out) {
    int i = blockIdx.x * 256 + threadIdx.x;
    if (i >= BB * PP) return;
    int b = i / PP, row = i - b * PP;
    float m = -1e30f, s = 0.f;
#pragma unroll
    for (int g = 0; g < NCG; ++g) {
        size_t o = ((size_t)b * NCG + g) * 960 + row;
        lse_merge(m, s, pm[o], ps[o]);
    }
    out[i] = m + logf(s) - pos[(size_t)b * 960 + row];
}

extern "C" void kernel_launch(void* const* d_in, const int* in_sizes, int n_in,
                              void* d_out, int out_size, void* d_ws, size_t ws_size,
                              hipStream_t stream) {
    const float* fq   = (const float*)d_in[0];
    const float* fk   = (const float*)d_in[1];
    const int*   sidx = (const int*)d_in[2];
    float* outp = (float*)d_out;

    char* p = (char*)d_ws;
    unsigned short* xqh = (unsigned short*)p; p += PLANE * 2;
    unsigned short* xql = (unsigned short*)p; p += PLANE * 2;
    unsigned short* xkh = (unsigned short*)p; p += PLANE * 2;
    unsigned short* xkl = (unsigned short*)p; p += PLANE * 2;
    int*          clist = (int*)p;            p += (size_t)BB * NCHK * MAXE * 4;
    int*           ccnt = (int*)p;            p += (size_t)BB * NCHK * 4;
    float*          pos = (float*)p;          p += (size_t)BB * 960 * 4;
    float*           pm = (float*)p;          p += (size_t)BB * NCG * 960 * 4;
    float*           ps = (float*)p;

    mapbuild_kernel<<<dim3(BB), 1024, 0, stream>>>(sidx, clist, ccnt);
    gather_kernel<<<dim3(4096), 256, 0, stream>>>(fq, fk, clist, ccnt, xqh, xql, xkh, xkl);
    nce_mfma<<<dim3(NCG, 8, BB), 512, 0, stream>>>(xqh, xql, xkh, xkl, pos, pm, ps);
    finalize_kernel<<<dim3((BB * PP + 255) / 256), 256, 0, stream>>>(pm, ps, pos, outp);
}